// Round 11
// baseline (318.594 us; speedup 1.0000x reference)
//
#include <hip/hip_runtime.h>
#include <stdint.h>

#define BATCH 256
#define NV 10475
#define NVP 10496        // NV padded to 164 tiles of 64
#define NJ 55
#define PB 486           // (NJ-1)*9
#define KS 506           // PB + 10 betas + 10 exprs
#define VC (NV*3)        // 31425
#define KP 512           // K padded to 16 chunks of 32
#define BKC 32
#define NCHUNK 16
#define BNV 16           // k_vposed col-tile (was 64): 4x blocks for latency hiding
#define JCH 8
#define JCHUNK 1312      // 8*1312 >= NV

typedef short bf16x8 __attribute__((ext_vector_type(8)));
typedef float f32x4  __attribute__((ext_vector_type(4)));

__constant__ int c_parents[NJ] = {
  -1,0,0,0,1,2,3,4,5,6,7,8,9,9,9,12,13,14,16,17,18,19,15,15,15,
  20,25,26,20,28,29,20,31,32,20,34,35,20,37,38,21,40,41,21,43,44,
  21,46,47,21,49,50,21,52,53};

// tree depth of each joint (max 10)
__constant__ int c_depth[NJ] = {
  0,1,1,1,2,2,2,3,3,3,4,4,4,4,4,5,5,5,6,6,7,7,6,6,6,
  8,9,10,8,9,10,8,9,10,8,9,10,8,9,10,
  8,9,10,8,9,10,8,9,10,8,9,10,8,9,10};

__device__ __forceinline__ unsigned short f2bf(float x){   // RNE fp32->bf16
  uint32_t u = __float_as_uint(x);
  uint32_t r = (u + 0x7fffu + ((u >> 16) & 1u)) >> 16;
  return (unsigned short)r;
}
__device__ __forceinline__ float bf2f(unsigned short h){
  return __uint_as_float(((uint32_t)h) << 16);
}

// ---------------- full_pose gather helper ----------------------------------
__device__ __forceinline__ const float* pose_src(int j, int b,
    const float* wrot, const float* bpose, const float* jaw, const float* leye,
    const float* reye, const float* lhand, const float* rhand) {
  if (j==0)  return wrot  + b*9;
  if (j<=21) return bpose + (b*21 + (j-1))*9;
  if (j==22) return jaw   + b*9;
  if (j==23) return leye  + b*9;
  if (j==24) return reye  + b*9;
  if (j<=39) return lhand + (b*15 + (j-25))*9;
  return rhand + (b*15 + (j-40))*9;
}

#define LWB_BLOCKS 2624              // (NVP*64)/256
#define PF_BLOCKS  BATCH             // 256
#define JS_BLOCKS  (JCH*NJ)          // 440
#define FRONT_BLOCKS (LWB_BLOCKS + PF_BLOCKS + JS_BLOCKS)   // 3320

// ---------------- k_front: fused [lw->lwb prep | posefeat | jsmall] ---------
__global__ __launch_bounds__(256) void k_front(
    const float* __restrict__ lw,
    const float* __restrict__ bpose, const float* __restrict__ jaw,
    const float* __restrict__ leye, const float* __restrict__ reye,
    const float* __restrict__ lhand, const float* __restrict__ rhand,
    const float* __restrict__ bs, const float* __restrict__ es,
    const float* __restrict__ jreg, const float* __restrict__ sd,
    const float* __restrict__ ed, const float* __restrict__ vt,
    unsigned short* __restrict__ lwb, unsigned short* __restrict__ pfb,
    float* __restrict__ part) {
  const int bid = blockIdx.x, t = threadIdx.x;
  if (bid < LWB_BLOCKS) {
    // ---- lw -> bf16 hi/lo [NVP][64]
    int idx = bid*256 + t;                 // n*64 + j
    int n = idx >> 6, j = idx & 63;
    float v = (n < NV && j < NJ) ? lw[(size_t)n*NJ + j] : 0.f;
    unsigned short hi = f2bf(v);
    float lo = v - bf2f(hi);
    lwb[idx] = hi;
    lwb[(size_t)NVP*64 + idx] = f2bf(lo);
  } else if (bid < LWB_BLOCKS + PF_BLOCKS) {
    // ---- pose_feature row for batch b: [pf(486) | bs(10) | es(10) | 0]
    int b = bid - LWB_BLOCKS;
    #pragma unroll
    for (int half=0; half<2; half++){
      int tt = t + half*256;               // 0..511
      unsigned short o = 0;
      if (tt < PB){
        int jj = tt/9, rc = tt - jj*9;
        const float* rs = pose_src(jj+1, b, nullptr, bpose, jaw, leye, reye, lhand, rhand);
        float v = rs[rc];
        if (rc==0 || rc==4 || rc==8) v -= 1.0f;
        o = f2bf(v);
      } else if (tt < 496){
        o = f2bf(bs[b*10 + (tt-486)]);
      } else if (tt < KS){
        o = f2bf(es[b*10 + (tt-496)]);
      }
      pfb[(size_t)b*KP + tt] = o;
    }
  } else {
    // ---- JS = Jreg @ [sd | ed | vt] per-(joint,chunk) partials
    int idx = bid - (LWB_BLOCKS + PF_BLOCKS);
    int ch = idx & 7, j = idx >> 3;
    float acc[63];
    #pragma unroll
    for (int s=0;s<63;s++) acc[s]=0.f;
    int n0 = ch*JCHUNK, nend = min(n0+JCHUNK, NV);
    for (int n = n0 + t; n < nend; n += 256){
      float w = jreg[(size_t)j*NV + n];
      const float* sp = sd + (size_t)n*30;
      const float* ep = ed + (size_t)n*30;
      const float* vp = vt + (size_t)n*3;
      #pragma unroll
      for (int c=0;c<3;c++){
        #pragma unroll
        for (int q=0;q<10;q++){
          acc[c*21+q]    += w*sp[c*10+q];
          acc[c*21+10+q] += w*ep[c*10+q];
        }
        acc[c*21+20] += w*vp[c];
      }
    }
    #pragma unroll
    for (int s=0;s<63;s++){
      float a = acc[s];
      #pragma unroll
      for (int d=32; d>=1; d>>=1) a += __shfl_xor(a,d);
      acc[s]=a;
    }
    __shared__ float red[4][63];
    int w = t>>6, l = t&63;
    if (l==0){
      #pragma unroll
      for (int s=0;s<63;s++) red[w][s]=acc[s];
    }
    __syncthreads();
    if (t < 63){
      float a = red[0][t]+red[1][t]+red[2][t]+red[3][t];
      part[((size_t)j*JCH+ch)*63 + t] = a;
    }
  }
}

// ---------------- k_mid: fused [joints2 + chain], one block per batch -------
__global__ __launch_bounds__(256) void k_mid(
    const float* __restrict__ part, const float* __restrict__ bs,
    const float* __restrict__ es,
    const float* __restrict__ wrot, const float* __restrict__ bpose,
    const float* __restrict__ jaw, const float* __restrict__ leye,
    const float* __restrict__ reye, const float* __restrict__ lhand,
    const float* __restrict__ rhand, const float* __restrict__ wtsl,
    unsigned short* __restrict__ arelb, float* __restrict__ jout) {
  __shared__ float jlds[NJ*3];
  const int b = blockIdx.x, t = threadIdx.x;
  if (t < NJ*3){
    int j = t/3, c = t - j*3;
    float S[21];
    #pragma unroll
    for (int q=0;q<21;q++) S[q]=0.f;
    for (int ch=0; ch<JCH; ch++){
      const float* p = part + ((size_t)j*JCH+ch)*63 + c*21;
      #pragma unroll
      for (int q=0;q<21;q++) S[q] += p[q];
    }
    float a = S[20];
    #pragma unroll
    for (int q=0;q<10;q++) a += S[q]*bs[b*10+q] + S[10+q]*es[b*10+q];
    jlds[t] = a;
  }
  __syncthreads();
  if (t >= 64) return;                     // wave 0 only below
  const int j = t;                         // lane = joint
  const bool act = (j < NJ);

  float R[9] = {1.f,0.f,0.f, 0.f,1.f,0.f, 0.f,0.f,1.f};
  if (act){
    const float* rs = pose_src(j, b, wrot, bpose, jaw, leye, reye, lhand, rhand);
    #pragma unroll
    for (int i=0;i<9;i++) R[i]=rs[i];
  }
  float jx=0.f, jy=0.f, jz=0.f;
  if (act){ jx=jlds[j*3+0]; jy=jlds[j*3+1]; jz=jlds[j*3+2]; }
  int par = act ? c_parents[j] : 0;
  if (par < 0) par = 0;
  float px = __shfl(jx, par), py = __shfl(jy, par), pz = __shfl(jz, par);
  float t0, t1, t2;
  if (j == 0){ t0=jx; t1=jy; t2=jz; }
  else       { t0=jx-px; t1=jy-py; t2=jz-pz; }

  float M[12];
  #pragma unroll
  for (int r=0;r<3;r++){
    M[r*4+0]=R[r*3+0]; M[r*4+1]=R[r*3+1]; M[r*4+2]=R[r*3+2]; M[r*4+3]= (r==0?t0:(r==1?t1:t2));
  }
  int dep = act ? c_depth[j] : 99;

  #pragma unroll
  for (int L=1; L<=10; L++){
    float pm[12];
    #pragma unroll
    for (int i=0;i<12;i++) pm[i] = __shfl(M[i], par);   // exec-uniform
    if (dep == L){
      #pragma unroll
      for (int r=0;r<3;r++){
        float p0=pm[r*4+0], p1=pm[r*4+1], p2=pm[r*4+2], p3=pm[r*4+3];
        M[r*4+0] = p0*R[0]+p1*R[3]+p2*R[6];
        M[r*4+1] = p0*R[1]+p1*R[4]+p2*R[7];
        M[r*4+2] = p0*R[2]+p1*R[5]+p2*R[8];
        M[r*4+3] = p0*t0 + p1*t1 + p2*t2 + p3;
      }
    }
  }

  float wx=wtsl[b*3+0], wy=wtsl[b*3+1], wz=wtsl[b*3+2];
  if (act){
    jout[((size_t)b*NJ+j)*3+0] = M[3]  + wx;
    jout[((size_t)b*NJ+j)*3+1] = M[7]  + wy;
    jout[((size_t)b*NJ+j)*3+2] = M[11] + wz;
  }
  float A[12];
  #pragma unroll
  for (int r=0;r<3;r++){
    A[r*4+0]=M[r*4+0]; A[r*4+1]=M[r*4+1]; A[r*4+2]=M[r*4+2];
    A[r*4+3]=M[r*4+3] - (M[r*4+0]*jx + M[r*4+1]*jy + M[r*4+2]*jz);
  }
  unsigned short* ah = arelb + (size_t)(b*2+0)*16*64;
  unsigned short* al = arelb + (size_t)(b*2+1)*16*64;
  #pragma unroll
  for (int e=0;e<16;e++){
    float v = (e < 12 && act) ? A[e] : 0.f;
    unsigned short hi = f2bf(v);
    float lo = v - bf2f(hi);
    ah[e*64 + j] = hi;                 // contiguous across lanes per e
    al[e*64 + j] = f2bf(lo);
  }
}

// -------- v_posed = [pf|bs|es] @ [posedirs; sdT; edT] + vt  (bf16 MFMA) -----
// BNV=16 col-tile: 1965 blocks (was 492) -> ~4x resident waves to hide the
// strided-pd HBM latency. Each block still reads its pd columns exactly once.
// Per wave: 4 row-tiles (mi) x 1 col-tile, acc[4] f32x4 (~55 VGPR).
__global__ __launch_bounds__(256) void k_vposed(
    const float* __restrict__ pd, const float* __restrict__ sd,
    const float* __restrict__ ed, const float* __restrict__ vt,
    const unsigned short* __restrict__ pfb, float* __restrict__ vsh) {
  const int tid  = threadIdx.x;
  const int w    = tid >> 6, lane = tid & 63;
  const int m16  = lane & 15, quad = lane >> 4;
  const int col0 = blockIdx.x * BNV;

  f32x4 acc[4];
  #pragma unroll
  for (int i=0;i<4;i++) acc[i] = (f32x4){0.f,0.f,0.f,0.f};

  const int bcol = min(col0 + m16, VC-1);  // clamped; clamped cols never stored

  const unsigned short* pfa = pfb + (size_t)(w*64 + m16)*KP + quad*8;

  #pragma unroll 2
  for (int c=0; c<15; c++){
    const int k0 = c*BKC;
    bf16x8 a[4];
    #pragma unroll
    for (int mi=0;mi<4;mi++)
      a[mi] = *((const bf16x8*)(pfa + (size_t)mi*16*KP + k0));
    union { bf16x8 v; unsigned short s[8]; } bb;
    #pragma unroll
    for (int j=0;j<8;j++){
      int kk = k0 + quad*8 + j;
      bb.s[j] = f2bf(pd[(size_t)kk*VC + bcol]);
    }
    #pragma unroll
    for (int mi=0;mi<4;mi++)
      acc[mi] = __builtin_amdgcn_mfma_f32_16x16x32_bf16(a[mi], bb.v, acc[mi], 0, 0, 0);
  }
  {
    const int k0 = 15*BKC;
    bf16x8 a[4];
    #pragma unroll
    for (int mi=0;mi<4;mi++)
      a[mi] = *((const bf16x8*)(pfa + (size_t)mi*16*KP + k0));
    union { bf16x8 v; unsigned short s[8]; } bb;
    int n3 = bcol/3, c3 = bcol - n3*3;
    const float* sp = sd + (size_t)n3*30 + c3*10;
    const float* ep = ed + (size_t)n3*30 + c3*10;
    #pragma unroll
    for (int j=0;j<8;j++){
      int kk = k0 + quad*8 + j;
      float f = 0.f;
      if (kk < PB)      f = pd[(size_t)kk*VC + bcol];
      else if (kk < KS){
        int q = kk - PB;                 // 0..19
        f = (q < 10) ? sp[q] : ep[q-10];
      }
      bb.s[j] = f2bf(f);
    }
    #pragma unroll
    for (int mi=0;mi<4;mi++)
      acc[mi] = __builtin_amdgcn_mfma_f32_16x16x32_bf16(a[mi], bb.v, acc[mi], 0, 0, 0);
  }
  // epilogue: vsh[row][col] = acc + v_template[col]
  const int col = col0 + m16;
  if (col < VC){
    float vtc = vt[col];
    #pragma unroll
    for (int mi=0;mi<4;mi++){
      int rbase = w*64 + mi*16 + quad*4;
      #pragma unroll
      for (int r=0;r<4;r++)
        vsh[(size_t)(rbase + r)*VC + col] = acc[mi][r] + vtc;
    }
  }
}

// -------- skinning: operand-swapped MFMA + per-wave LDS slot + coalesced apply
// 8 batches/block (was 16): grid 164x32 = 5248 blocks (was 2624) -> 2x
// resident blocks / outstanding loads. lwb re-reads double but are L2/L3-hot.
__global__ __launch_bounds__(256) void k_verts(
    const unsigned short* __restrict__ lwb, const unsigned short* __restrict__ arelb,
    const float* __restrict__ wtsl, float* __restrict__ out) {
  __shared__ float sT[4*816];              // 4 wave slots x 12 planes x 68
  const int tid = threadIdx.x, w = tid >> 6, lane = tid & 63;
  const int m16 = lane & 15, quad = lane >> 4;   // quad = T row q
  const int n0 = blockIdx.x*64;
  const int b0 = blockIdx.y*8;
  float* myT = &sT[w*816];

  bf16x8 lwh[4][2], lwl[4][2];
  #pragma unroll
  for (int vt4=0; vt4<4; vt4++){
    int row = n0 + vt4*16 + m16;
    #pragma unroll
    for (int kc=0;kc<2;kc++){
      lwh[vt4][kc] = *((const bf16x8*)(lwb + (size_t)row*64 + kc*32 + quad*8));
      lwl[vt4][kc] = *((const bf16x8*)(lwb + (size_t)NVP*64 + (size_t)row*64 + kc*32 + quad*8));
    }
  }
  const int nA = n0 + lane;                // apply vert for this lane
  const bool okA = (nA < NV);

  for (int bi=0; bi<2; bi++){
    const int b = b0 + w*2 + bi;
    bf16x8 ah[2], al[2];
    #pragma unroll
    for (int kc=0;kc<2;kc++){
      ah[kc] = *((const bf16x8*)(arelb + ((size_t)(b*2+0)*16 + m16)*64 + kc*32 + quad*8));
      al[kc] = *((const bf16x8*)(arelb + ((size_t)(b*2+1)*16 + m16)*64 + kc*32 + quad*8));
    }
    const float* vp = out + ((size_t)b*NV + nA)*3;
    float vx = okA ? vp[0] : 0.f;
    float vy = okA ? vp[1] : 0.f;
    float vz = okA ? vp[2] : 0.f;

    f32x4 acc[4];
    #pragma unroll
    for (int vt4=0; vt4<4; vt4++) acc[vt4] = (f32x4){0.f,0.f,0.f,0.f};
    #pragma unroll
    for (int vt4=0; vt4<4; vt4++){
      #pragma unroll
      for (int kc=0;kc<2;kc++){
        acc[vt4] = __builtin_amdgcn_mfma_f32_16x16x32_bf16(ah[kc], lwh[vt4][kc], acc[vt4], 0,0,0);
        acc[vt4] = __builtin_amdgcn_mfma_f32_16x16x32_bf16(al[kc], lwh[vt4][kc], acc[vt4], 0,0,0);
        acc[vt4] = __builtin_amdgcn_mfma_f32_16x16x32_bf16(ah[kc], lwl[vt4][kc], acc[vt4], 0,0,0);
      }
    }
    #pragma unroll
    for (int vt4=0; vt4<4; vt4++){
      if (quad < 3){
        #pragma unroll
        for (int r=0;r<4;r++)
          myT[(quad*4 + r)*68 + vt4*16 + m16] = acc[vt4][r];
      }
    }
    float T[12];
    #pragma unroll
    for (int e=0;e<12;e++) T[e] = myT[e*68 + lane];
    if (okA){
      float tx=wtsl[b*3+0], ty=wtsl[b*3+1], tz=wtsl[b*3+2];
      float* op = out + ((size_t)b*NV + nA)*3;
      op[0] = T[0]*vx + T[1]*vy + T[2] *vz + T[3]  + tx;
      op[1] = T[4]*vx + T[5]*vy + T[6] *vz + T[7]  + ty;
      op[2] = T[8]*vx + T[9]*vy + T[10]*vz + T[11] + tz;
    }
  }
}

extern "C" void kernel_launch(void* const* d_in, const int* in_sizes, int n_in,
                              void* d_out, int out_size, void* d_ws, size_t ws_size,
                              hipStream_t stream) {
  const float* wrot   = (const float*)d_in[0];
  const float* wtsl   = (const float*)d_in[1];
  const float* bshape = (const float*)d_in[2];
  const float* bpose  = (const float*)d_in[3];
  const float* lhand  = (const float*)d_in[4];
  const float* rhand  = (const float*)d_in[5];
  const float* eshape = (const float*)d_in[6];
  const float* jaw    = (const float*)d_in[7];
  const float* leye   = (const float*)d_in[8];
  const float* reye   = (const float*)d_in[9];
  const float* vt     = (const float*)d_in[10];
  const float* sd     = (const float*)d_in[11];
  const float* ed     = (const float*)d_in[12];
  const float* pd     = (const float*)d_in[13];
  const float* jreg   = (const float*)d_in[14];
  const float* lw     = (const float*)d_in[15];
  float* out = (float*)d_out;

  float* vsh  = out;                               // verts region = v_posed scratch
  float* jout = out + (size_t)BATCH*NV*3;

  float* ws   = (float*)d_ws;
  float* part = ws;                                        // 55*8*63 = 27720
  unsigned short* pfb   = (unsigned short*)(part + (size_t)NJ*JCH*63); // 256*512
  unsigned short* lwb   = pfb + (size_t)BATCH*KP;                     // 2*NVP*64
  unsigned short* arelb = lwb + (size_t)2*NVP*64;                     // 256*2*16*64

  k_front <<<FRONT_BLOCKS, 256, 0, stream>>>(lw, bpose, jaw, leye, reye,
                                             lhand, rhand, bshape, eshape,
                                             jreg, sd, ed, vt, lwb, pfb, part);
  k_mid   <<<BATCH, 256, 0, stream>>>(part, bshape, eshape, wrot, bpose, jaw,
                                      leye, reye, lhand, rhand, wtsl, arelb, jout);
  k_vposed<<<(VC+BNV-1)/BNV, 256, 0, stream>>>(pd, sd, ed, vt, pfb, vsh);
  k_verts <<<dim3(NVP/64, BATCH/8), 256, 0, stream>>>(lwb, arelb, wtsl, out);
}

// Round 12
// 266.212 us; speedup vs baseline: 1.1968x; 1.1968x over previous
//
#include <hip/hip_runtime.h>
#include <stdint.h>

#define BATCH 256
#define NV 10475
#define NVP 10496        // NV padded to 164 tiles of 64
#define NJ 55
#define PB 486           // (NJ-1)*9
#define KS 506           // PB + 10 betas + 10 exprs
#define VC (NV*3)        // 31425
#define KP 512           // K padded to 16 chunks of 32
#define BKC 32
#define NCHUNK 16
#define BN 64
#define JCH 8
#define JCHUNK 1312      // 8*1312 >= NV

typedef short bf16x8 __attribute__((ext_vector_type(8)));
typedef float f32x4  __attribute__((ext_vector_type(4)));

__constant__ int c_parents[NJ] = {
  -1,0,0,0,1,2,3,4,5,6,7,8,9,9,9,12,13,14,16,17,18,19,15,15,15,
  20,25,26,20,28,29,20,31,32,20,34,35,20,37,38,21,40,41,21,43,44,
  21,46,47,21,49,50,21,52,53};

// tree depth of each joint (max 10)
__constant__ int c_depth[NJ] = {
  0,1,1,1,2,2,2,3,3,3,4,4,4,4,4,5,5,5,6,6,7,7,6,6,6,
  8,9,10,8,9,10,8,9,10,8,9,10,8,9,10,
  8,9,10,8,9,10,8,9,10,8,9,10,8,9,10};

__device__ __forceinline__ unsigned short f2bf(float x){   // RNE fp32->bf16
  uint32_t u = __float_as_uint(x);
  uint32_t r = (u + 0x7fffu + ((u >> 16) & 1u)) >> 16;
  return (unsigned short)r;
}
__device__ __forceinline__ float bf2f(unsigned short h){
  return __uint_as_float(((uint32_t)h) << 16);
}

// ---------------- full_pose gather helper ----------------------------------
__device__ __forceinline__ const float* pose_src(int j, int b,
    const float* wrot, const float* bpose, const float* jaw, const float* leye,
    const float* reye, const float* lhand, const float* rhand) {
  if (j==0)  return wrot  + b*9;
  if (j<=21) return bpose + (b*21 + (j-1))*9;
  if (j==22) return jaw   + b*9;
  if (j==23) return leye  + b*9;
  if (j==24) return reye  + b*9;
  if (j<=39) return lhand + (b*15 + (j-25))*9;
  return rhand + (b*15 + (j-40))*9;
}

#define LWB_BLOCKS 2624              // (NVP*64)/256
#define PF_BLOCKS  BATCH             // 256
#define JS_BLOCKS  (JCH*NJ)          // 440
#define FRONT_BLOCKS (LWB_BLOCKS + PF_BLOCKS + JS_BLOCKS)   // 3320

// ---------------- k_front: fused [lw->lwb prep | posefeat | jsmall] ---------
__global__ __launch_bounds__(256) void k_front(
    const float* __restrict__ lw,
    const float* __restrict__ bpose, const float* __restrict__ jaw,
    const float* __restrict__ leye, const float* __restrict__ reye,
    const float* __restrict__ lhand, const float* __restrict__ rhand,
    const float* __restrict__ bs, const float* __restrict__ es,
    const float* __restrict__ jreg, const float* __restrict__ sd,
    const float* __restrict__ ed, const float* __restrict__ vt,
    unsigned short* __restrict__ lwb, unsigned short* __restrict__ pfb,
    float* __restrict__ part) {
  const int bid = blockIdx.x, t = threadIdx.x;
  if (bid < LWB_BLOCKS) {
    // ---- lw -> bf16 hi/lo [NVP][64]
    int idx = bid*256 + t;                 // n*64 + j
    int n = idx >> 6, j = idx & 63;
    float v = (n < NV && j < NJ) ? lw[(size_t)n*NJ + j] : 0.f;
    unsigned short hi = f2bf(v);
    float lo = v - bf2f(hi);
    lwb[idx] = hi;
    lwb[(size_t)NVP*64 + idx] = f2bf(lo);
  } else if (bid < LWB_BLOCKS + PF_BLOCKS) {
    // ---- pose_feature row for batch b: [pf(486) | bs(10) | es(10) | 0]
    int b = bid - LWB_BLOCKS;
    #pragma unroll
    for (int half=0; half<2; half++){
      int tt = t + half*256;               // 0..511
      unsigned short o = 0;
      if (tt < PB){
        int jj = tt/9, rc = tt - jj*9;
        const float* rs = pose_src(jj+1, b, nullptr, bpose, jaw, leye, reye, lhand, rhand);
        float v = rs[rc];
        if (rc==0 || rc==4 || rc==8) v -= 1.0f;
        o = f2bf(v);
      } else if (tt < 496){
        o = f2bf(bs[b*10 + (tt-486)]);
      } else if (tt < KS){
        o = f2bf(es[b*10 + (tt-496)]);
      }
      pfb[(size_t)b*KP + tt] = o;
    }
  } else {
    // ---- JS = Jreg @ [sd | ed | vt] per-(joint,chunk) partials
    int idx = bid - (LWB_BLOCKS + PF_BLOCKS);
    int ch = idx & 7, j = idx >> 3;
    float acc[63];
    #pragma unroll
    for (int s=0;s<63;s++) acc[s]=0.f;
    int n0 = ch*JCHUNK, nend = min(n0+JCHUNK, NV);
    for (int n = n0 + t; n < nend; n += 256){
      float w = jreg[(size_t)j*NV + n];
      const float* sp = sd + (size_t)n*30;
      const float* ep = ed + (size_t)n*30;
      const float* vp = vt + (size_t)n*3;
      #pragma unroll
      for (int c=0;c<3;c++){
        #pragma unroll
        for (int q=0;q<10;q++){
          acc[c*21+q]    += w*sp[c*10+q];
          acc[c*21+10+q] += w*ep[c*10+q];
        }
        acc[c*21+20] += w*vp[c];
      }
    }
    #pragma unroll
    for (int s=0;s<63;s++){
      float a = acc[s];
      #pragma unroll
      for (int d=32; d>=1; d>>=1) a += __shfl_xor(a,d);
      acc[s]=a;
    }
    __shared__ float red[4][63];
    int w = t>>6, l = t&63;
    if (l==0){
      #pragma unroll
      for (int s=0;s<63;s++) red[w][s]=acc[s];
    }
    __syncthreads();
    if (t < 63){
      float a = red[0][t]+red[1][t]+red[2][t]+red[3][t];
      part[((size_t)j*JCH+ch)*63 + t] = a;
    }
  }
}

// ---------------- k_mid: fused [joints2 + chain], one block per batch -------
__global__ __launch_bounds__(256) void k_mid(
    const float* __restrict__ part, const float* __restrict__ bs,
    const float* __restrict__ es,
    const float* __restrict__ wrot, const float* __restrict__ bpose,
    const float* __restrict__ jaw, const float* __restrict__ leye,
    const float* __restrict__ reye, const float* __restrict__ lhand,
    const float* __restrict__ rhand, const float* __restrict__ wtsl,
    unsigned short* __restrict__ arelb, float* __restrict__ jout) {
  __shared__ float jlds[NJ*3];
  const int b = blockIdx.x, t = threadIdx.x;
  if (t < NJ*3){
    int j = t/3, c = t - j*3;
    float S[21];
    #pragma unroll
    for (int q=0;q<21;q++) S[q]=0.f;
    for (int ch=0; ch<JCH; ch++){
      const float* p = part + ((size_t)j*JCH+ch)*63 + c*21;
      #pragma unroll
      for (int q=0;q<21;q++) S[q] += p[q];
    }
    float a = S[20];
    #pragma unroll
    for (int q=0;q<10;q++) a += S[q]*bs[b*10+q] + S[10+q]*es[b*10+q];
    jlds[t] = a;
  }
  __syncthreads();
  if (t >= 64) return;                     // wave 0 only below
  const int j = t;                         // lane = joint
  const bool act = (j < NJ);

  float R[9] = {1.f,0.f,0.f, 0.f,1.f,0.f, 0.f,0.f,1.f};
  if (act){
    const float* rs = pose_src(j, b, wrot, bpose, jaw, leye, reye, lhand, rhand);
    #pragma unroll
    for (int i=0;i<9;i++) R[i]=rs[i];
  }
  float jx=0.f, jy=0.f, jz=0.f;
  if (act){ jx=jlds[j*3+0]; jy=jlds[j*3+1]; jz=jlds[j*3+2]; }
  int par = act ? c_parents[j] : 0;
  if (par < 0) par = 0;
  float px = __shfl(jx, par), py = __shfl(jy, par), pz = __shfl(jz, par);
  float t0, t1, t2;
  if (j == 0){ t0=jx; t1=jy; t2=jz; }
  else       { t0=jx-px; t1=jy-py; t2=jz-pz; }

  float M[12];
  #pragma unroll
  for (int r=0;r<3;r++){
    M[r*4+0]=R[r*3+0]; M[r*4+1]=R[r*3+1]; M[r*4+2]=R[r*3+2]; M[r*4+3]= (r==0?t0:(r==1?t1:t2));
  }
  int dep = act ? c_depth[j] : 99;

  #pragma unroll
  for (int L=1; L<=10; L++){
    float pm[12];
    #pragma unroll
    for (int i=0;i<12;i++) pm[i] = __shfl(M[i], par);   // exec-uniform
    if (dep == L){
      #pragma unroll
      for (int r=0;r<3;r++){
        float p0=pm[r*4+0], p1=pm[r*4+1], p2=pm[r*4+2], p3=pm[r*4+3];
        M[r*4+0] = p0*R[0]+p1*R[3]+p2*R[6];
        M[r*4+1] = p0*R[1]+p1*R[4]+p2*R[7];
        M[r*4+2] = p0*R[2]+p1*R[5]+p2*R[8];
        M[r*4+3] = p0*t0 + p1*t1 + p2*t2 + p3;
      }
    }
  }

  float wx=wtsl[b*3+0], wy=wtsl[b*3+1], wz=wtsl[b*3+2];
  if (act){
    jout[((size_t)b*NJ+j)*3+0] = M[3]  + wx;
    jout[((size_t)b*NJ+j)*3+1] = M[7]  + wy;
    jout[((size_t)b*NJ+j)*3+2] = M[11] + wz;
  }
  float A[12];
  #pragma unroll
  for (int r=0;r<3;r++){
    A[r*4+0]=M[r*4+0]; A[r*4+1]=M[r*4+1]; A[r*4+2]=M[r*4+2];
    A[r*4+3]=M[r*4+3] - (M[r*4+0]*jx + M[r*4+1]*jy + M[r*4+2]*jz);
  }
  unsigned short* ah = arelb + (size_t)(b*2+0)*16*64;
  unsigned short* al = arelb + (size_t)(b*2+1)*16*64;
  #pragma unroll
  for (int e=0;e<16;e++){
    float v = (e < 12 && act) ? A[e] : 0.f;
    unsigned short hi = f2bf(v);
    float lo = v - bf2f(hi);
    ah[e*64 + j] = hi;                 // contiguous across lanes per e
    al[e*64 + j] = f2bf(lo);
  }
}

// -------- v_posed = [pf|bs|es] @ [posedirs; sdT; edT] + vt  (bf16 MFMA) -----
// BN=64 (full 256 B/row/block fetch granularity — R11's BNV=16 halved line
// utilization, FETCH 47->91 MB) but 512 threads / 8 waves: each wave computes
// 32 batch-rows (acc[2][4]), occupancy cap 7.7 -> 15.4 waves/CU at the same
// grid (492) and same HBM footprint. Duplicated B-loads across waves hit L1/L2.
__global__ __launch_bounds__(512) void k_vposed(
    const float* __restrict__ pd, const float* __restrict__ sd,
    const float* __restrict__ ed, const float* __restrict__ vt,
    const unsigned short* __restrict__ pfb, float* __restrict__ vsh) {
  const int tid  = threadIdx.x;
  const int w    = tid >> 6, lane = tid & 63;      // w = 0..7
  const int m16  = lane & 15, quad = lane >> 4;
  const int col0 = blockIdx.x * BN;

  f32x4 acc[2][4];
  #pragma unroll
  for (int i=0;i<2;i++)
    #pragma unroll
    for (int j=0;j<4;j++) acc[i][j] = (f32x4){0.f,0.f,0.f,0.f};

  int bcol[4];
  #pragma unroll
  for (int ni=0;ni<4;ni++) bcol[ni] = min(col0 + ni*16 + m16, VC-1);

  const unsigned short* pfa = pfb + (size_t)(w*32 + m16)*KP + quad*8;

  #pragma unroll 2
  for (int c=0; c<15; c++){
    const int k0 = c*BKC;
    bf16x8 a[2];
    #pragma unroll
    for (int mi=0;mi<2;mi++)
      a[mi] = *((const bf16x8*)(pfa + (size_t)mi*16*KP + k0));
    union { bf16x8 v; unsigned short s[8]; } bb[4];
    #pragma unroll
    for (int ni=0;ni<4;ni++){
      #pragma unroll
      for (int j=0;j<8;j++){
        int kk = k0 + quad*8 + j;
        bb[ni].s[j] = f2bf(pd[(size_t)kk*VC + bcol[ni]]);
      }
    }
    #pragma unroll
    for (int mi=0;mi<2;mi++)
      #pragma unroll
      for (int ni=0;ni<4;ni++)
        acc[mi][ni] = __builtin_amdgcn_mfma_f32_16x16x32_bf16(
                          a[mi], bb[ni].v, acc[mi][ni], 0, 0, 0);
  }
  {
    const int k0 = 15*BKC;
    bf16x8 a[2];
    #pragma unroll
    for (int mi=0;mi<2;mi++)
      a[mi] = *((const bf16x8*)(pfa + (size_t)mi*16*KP + k0));
    union { bf16x8 v; unsigned short s[8]; } bb[4];
    #pragma unroll
    for (int ni=0;ni<4;ni++){
      int n3 = bcol[ni]/3, c3 = bcol[ni] - n3*3;
      const float* sp = sd + (size_t)n3*30 + c3*10;
      const float* ep = ed + (size_t)n3*30 + c3*10;
      #pragma unroll
      for (int j=0;j<8;j++){
        int kk = k0 + quad*8 + j;
        float f = 0.f;
        if (kk < PB)      f = pd[(size_t)kk*VC + bcol[ni]];
        else if (kk < KS){
          int q = kk - PB;                 // 0..19
          f = (q < 10) ? sp[q] : ep[q-10];
        }
        bb[ni].s[j] = f2bf(f);
      }
    }
    #pragma unroll
    for (int mi=0;mi<2;mi++)
      #pragma unroll
      for (int ni=0;ni<4;ni++)
        acc[mi][ni] = __builtin_amdgcn_mfma_f32_16x16x32_bf16(
                          a[mi], bb[ni].v, acc[mi][ni], 0, 0, 0);
  }
  #pragma unroll
  for (int mi=0;mi<2;mi++){
    int rbase = w*32 + mi*16 + quad*4;
    #pragma unroll
    for (int ni=0;ni<4;ni++){
      int col = col0 + ni*16 + m16;
      if (col < VC){
        float vtc = vt[col];
        #pragma unroll
        for (int r=0;r<4;r++)
          vsh[(size_t)(rbase + r)*VC + col] = acc[mi][ni][r] + vtc;
      }
    }
  }
}

// -------- skinning: operand-swapped MFMA + per-wave LDS slot + coalesced apply
// (R10-proven form: 16 batches/block, 52.9 µs, zero conflicts)
__global__ __launch_bounds__(256) void k_verts(
    const unsigned short* __restrict__ lwb, const unsigned short* __restrict__ arelb,
    const float* __restrict__ wtsl, float* __restrict__ out) {
  __shared__ float sT[4*816];              // 4 wave slots x 12 planes x 68
  const int tid = threadIdx.x, w = tid >> 6, lane = tid & 63;
  const int m16 = lane & 15, quad = lane >> 4;   // quad = T row q
  const int n0 = blockIdx.x*64;
  const int b0 = blockIdx.y*16;
  float* myT = &sT[w*816];

  bf16x8 lwh[4][2], lwl[4][2];
  #pragma unroll
  for (int vt4=0; vt4<4; vt4++){
    int row = n0 + vt4*16 + m16;
    #pragma unroll
    for (int kc=0;kc<2;kc++){
      lwh[vt4][kc] = *((const bf16x8*)(lwb + (size_t)row*64 + kc*32 + quad*8));
      lwl[vt4][kc] = *((const bf16x8*)(lwb + (size_t)NVP*64 + (size_t)row*64 + kc*32 + quad*8));
    }
  }
  const int nA = n0 + lane;                // apply vert for this lane
  const bool okA = (nA < NV);

  for (int bi=0; bi<4; bi++){
    const int b = b0 + w*4 + bi;
    bf16x8 ah[2], al[2];
    #pragma unroll
    for (int kc=0;kc<2;kc++){
      ah[kc] = *((const bf16x8*)(arelb + ((size_t)(b*2+0)*16 + m16)*64 + kc*32 + quad*8));
      al[kc] = *((const bf16x8*)(arelb + ((size_t)(b*2+1)*16 + m16)*64 + kc*32 + quad*8));
    }
    const float* vp = out + ((size_t)b*NV + nA)*3;
    float vx = okA ? vp[0] : 0.f;
    float vy = okA ? vp[1] : 0.f;
    float vz = okA ? vp[2] : 0.f;

    f32x4 acc[4];
    #pragma unroll
    for (int vt4=0; vt4<4; vt4++) acc[vt4] = (f32x4){0.f,0.f,0.f,0.f};
    #pragma unroll
    for (int vt4=0; vt4<4; vt4++){
      #pragma unroll
      for (int kc=0;kc<2;kc++){
        acc[vt4] = __builtin_amdgcn_mfma_f32_16x16x32_bf16(ah[kc], lwh[vt4][kc], acc[vt4], 0,0,0);
        acc[vt4] = __builtin_amdgcn_mfma_f32_16x16x32_bf16(al[kc], lwh[vt4][kc], acc[vt4], 0,0,0);
        acc[vt4] = __builtin_amdgcn_mfma_f32_16x16x32_bf16(ah[kc], lwl[vt4][kc], acc[vt4], 0,0,0);
      }
    }
    #pragma unroll
    for (int vt4=0; vt4<4; vt4++){
      if (quad < 3){
        #pragma unroll
        for (int r=0;r<4;r++)
          myT[(quad*4 + r)*68 + vt4*16 + m16] = acc[vt4][r];
      }
    }
    float T[12];
    #pragma unroll
    for (int e=0;e<12;e++) T[e] = myT[e*68 + lane];
    if (okA){
      float tx=wtsl[b*3+0], ty=wtsl[b*3+1], tz=wtsl[b*3+2];
      float* op = out + ((size_t)b*NV + nA)*3;
      op[0] = T[0]*vx + T[1]*vy + T[2] *vz + T[3]  + tx;
      op[1] = T[4]*vx + T[5]*vy + T[6] *vz + T[7]  + ty;
      op[2] = T[8]*vx + T[9]*vy + T[10]*vz + T[11] + tz;
    }
  }
}

extern "C" void kernel_launch(void* const* d_in, const int* in_sizes, int n_in,
                              void* d_out, int out_size, void* d_ws, size_t ws_size,
                              hipStream_t stream) {
  const float* wrot   = (const float*)d_in[0];
  const float* wtsl   = (const float*)d_in[1];
  const float* bshape = (const float*)d_in[2];
  const float* bpose  = (const float*)d_in[3];
  const float* lhand  = (const float*)d_in[4];
  const float* rhand  = (const float*)d_in[5];
  const float* eshape = (const float*)d_in[6];
  const float* jaw    = (const float*)d_in[7];
  const float* leye   = (const float*)d_in[8];
  const float* reye   = (const float*)d_in[9];
  const float* vt     = (const float*)d_in[10];
  const float* sd     = (const float*)d_in[11];
  const float* ed     = (const float*)d_in[12];
  const float* pd     = (const float*)d_in[13];
  const float* jreg   = (const float*)d_in[14];
  const float* lw     = (const float*)d_in[15];
  float* out = (float*)d_out;

  float* vsh  = out;                               // verts region = v_posed scratch
  float* jout = out + (size_t)BATCH*NV*3;

  float* ws   = (float*)d_ws;
  float* part = ws;                                        // 55*8*63 = 27720
  unsigned short* pfb   = (unsigned short*)(part + (size_t)NJ*JCH*63); // 256*512
  unsigned short* lwb   = pfb + (size_t)BATCH*KP;                     // 2*NVP*64
  unsigned short* arelb = lwb + (size_t)2*NVP*64;                     // 256*2*16*64

  k_front <<<FRONT_BLOCKS, 256, 0, stream>>>(lw, bpose, jaw, leye, reye,
                                             lhand, rhand, bshape, eshape,
                                             jreg, sd, ed, vt, lwb, pfb, part);
  k_mid   <<<BATCH, 256, 0, stream>>>(part, bshape, eshape, wrot, bpose, jaw,
                                      leye, reye, lhand, rhand, wtsl, arelb, jout);
  k_vposed<<<(VC+BN-1)/BN, 512, 0, stream>>>(pd, sd, ed, vt, pfb, vsh);
  k_verts <<<dim3(NVP/64, BATCH/16), 256, 0, stream>>>(lwb, arelb, wtsl, out);
}

// Round 13
// 240.462 us; speedup vs baseline: 1.3249x; 1.1071x over previous
//
#include <hip/hip_runtime.h>
#include <stdint.h>

#define BATCH 256
#define NV 10475
#define NVP 10496        // NV padded to 164 tiles of 64
#define NJ 55
#define PB 486           // (NJ-1)*9
#define KS 506           // PB + 10 betas + 10 exprs
#define VC (NV*3)        // 31425
#define KP 512           // K padded to 16 chunks of 32
#define BKC 32
#define NCHUNK 16
#define BN 64
#define PADC 70          // LDS row pitch (ushorts): (3k+col/2)%32 read banks conflict-free
#define JCH 8
#define JCHUNK 1312      // 8*1312 >= NV

typedef short bf16x8 __attribute__((ext_vector_type(8)));
typedef float f32x4  __attribute__((ext_vector_type(4)));

__constant__ int c_parents[NJ] = {
  -1,0,0,0,1,2,3,4,5,6,7,8,9,9,9,12,13,14,16,17,18,19,15,15,15,
  20,25,26,20,28,29,20,31,32,20,34,35,20,37,38,21,40,41,21,43,44,
  21,46,47,21,49,50,21,52,53};

// tree depth of each joint (max 10)
__constant__ int c_depth[NJ] = {
  0,1,1,1,2,2,2,3,3,3,4,4,4,4,4,5,5,5,6,6,7,7,6,6,6,
  8,9,10,8,9,10,8,9,10,8,9,10,8,9,10,
  8,9,10,8,9,10,8,9,10,8,9,10,8,9,10};

__device__ __forceinline__ unsigned short f2bf(float x){   // RNE fp32->bf16
  uint32_t u = __float_as_uint(x);
  uint32_t r = (u + 0x7fffu + ((u >> 16) & 1u)) >> 16;
  return (unsigned short)r;
}
__device__ __forceinline__ float bf2f(unsigned short h){
  return __uint_as_float(((uint32_t)h) << 16);
}

// ---------------- full_pose gather helper ----------------------------------
__device__ __forceinline__ const float* pose_src(int j, int b,
    const float* wrot, const float* bpose, const float* jaw, const float* leye,
    const float* reye, const float* lhand, const float* rhand) {
  if (j==0)  return wrot  + b*9;
  if (j<=21) return bpose + (b*21 + (j-1))*9;
  if (j==22) return jaw   + b*9;
  if (j==23) return leye  + b*9;
  if (j==24) return reye  + b*9;
  if (j<=39) return lhand + (b*15 + (j-25))*9;
  return rhand + (b*15 + (j-40))*9;
}

#define LWB_BLOCKS 2624              // (NVP*64)/256
#define PF_BLOCKS  BATCH             // 256
#define JS_BLOCKS  (JCH*NJ)          // 440
#define FRONT_BLOCKS (LWB_BLOCKS + PF_BLOCKS + JS_BLOCKS)   // 3320

// ---------------- k_front: fused [lw->lwb prep | posefeat | jsmall] ---------
__global__ __launch_bounds__(256) void k_front(
    const float* __restrict__ lw,
    const float* __restrict__ bpose, const float* __restrict__ jaw,
    const float* __restrict__ leye, const float* __restrict__ reye,
    const float* __restrict__ lhand, const float* __restrict__ rhand,
    const float* __restrict__ bs, const float* __restrict__ es,
    const float* __restrict__ jreg, const float* __restrict__ sd,
    const float* __restrict__ ed, const float* __restrict__ vt,
    unsigned short* __restrict__ lwb, unsigned short* __restrict__ pfb,
    float* __restrict__ part) {
  const int bid = blockIdx.x, t = threadIdx.x;
  if (bid < LWB_BLOCKS) {
    // ---- lw -> bf16 hi/lo [NVP][64]
    int idx = bid*256 + t;                 // n*64 + j
    int n = idx >> 6, j = idx & 63;
    float v = (n < NV && j < NJ) ? lw[(size_t)n*NJ + j] : 0.f;
    unsigned short hi = f2bf(v);
    float lo = v - bf2f(hi);
    lwb[idx] = hi;
    lwb[(size_t)NVP*64 + idx] = f2bf(lo);
  } else if (bid < LWB_BLOCKS + PF_BLOCKS) {
    // ---- pose_feature row for batch b: [pf(486) | bs(10) | es(10) | 0]
    int b = bid - LWB_BLOCKS;
    #pragma unroll
    for (int half=0; half<2; half++){
      int tt = t + half*256;               // 0..511
      unsigned short o = 0;
      if (tt < PB){
        int jj = tt/9, rc = tt - jj*9;
        const float* rs = pose_src(jj+1, b, nullptr, bpose, jaw, leye, reye, lhand, rhand);
        float v = rs[rc];
        if (rc==0 || rc==4 || rc==8) v -= 1.0f;
        o = f2bf(v);
      } else if (tt < 496){
        o = f2bf(bs[b*10 + (tt-486)]);
      } else if (tt < KS){
        o = f2bf(es[b*10 + (tt-496)]);
      }
      pfb[(size_t)b*KP + tt] = o;
    }
  } else {
    // ---- JS = Jreg @ [sd | ed | vt] per-(joint,chunk) partials
    int idx = bid - (LWB_BLOCKS + PF_BLOCKS);
    int ch = idx & 7, j = idx >> 3;
    float acc[63];
    #pragma unroll
    for (int s=0;s<63;s++) acc[s]=0.f;
    int n0 = ch*JCHUNK, nend = min(n0+JCHUNK, NV);
    for (int n = n0 + t; n < nend; n += 256){
      float w = jreg[(size_t)j*NV + n];
      const float* sp = sd + (size_t)n*30;
      const float* ep = ed + (size_t)n*30;
      const float* vp = vt + (size_t)n*3;
      #pragma unroll
      for (int c=0;c<3;c++){
        #pragma unroll
        for (int q=0;q<10;q++){
          acc[c*21+q]    += w*sp[c*10+q];
          acc[c*21+10+q] += w*ep[c*10+q];
        }
        acc[c*21+20] += w*vp[c];
      }
    }
    #pragma unroll
    for (int s=0;s<63;s++){
      float a = acc[s];
      #pragma unroll
      for (int d=32; d>=1; d>>=1) a += __shfl_xor(a,d);
      acc[s]=a;
    }
    __shared__ float red[4][63];
    int w = t>>6, l = t&63;
    if (l==0){
      #pragma unroll
      for (int s=0;s<63;s++) red[w][s]=acc[s];
    }
    __syncthreads();
    if (t < 63){
      float a = red[0][t]+red[1][t]+red[2][t]+red[3][t];
      part[((size_t)j*JCH+ch)*63 + t] = a;
    }
  }
}

// ---------------- k_mid: fused [joints2 + chain], one block per batch -------
__global__ __launch_bounds__(256) void k_mid(
    const float* __restrict__ part, const float* __restrict__ bs,
    const float* __restrict__ es,
    const float* __restrict__ wrot, const float* __restrict__ bpose,
    const float* __restrict__ jaw, const float* __restrict__ leye,
    const float* __restrict__ reye, const float* __restrict__ lhand,
    const float* __restrict__ rhand, const float* __restrict__ wtsl,
    unsigned short* __restrict__ arelb, float* __restrict__ jout) {
  __shared__ float jlds[NJ*3];
  const int b = blockIdx.x, t = threadIdx.x;
  if (t < NJ*3){
    int j = t/3, c = t - j*3;
    float S[21];
    #pragma unroll
    for (int q=0;q<21;q++) S[q]=0.f;
    for (int ch=0; ch<JCH; ch++){
      const float* p = part + ((size_t)j*JCH+ch)*63 + c*21;
      #pragma unroll
      for (int q=0;q<21;q++) S[q] += p[q];
    }
    float a = S[20];
    #pragma unroll
    for (int q=0;q<10;q++) a += S[q]*bs[b*10+q] + S[10+q]*es[b*10+q];
    jlds[t] = a;
  }
  __syncthreads();
  if (t >= 64) return;                     // wave 0 only below
  const int j = t;                         // lane = joint
  const bool act = (j < NJ);

  float R[9] = {1.f,0.f,0.f, 0.f,1.f,0.f, 0.f,0.f,1.f};
  if (act){
    const float* rs = pose_src(j, b, wrot, bpose, jaw, leye, reye, lhand, rhand);
    #pragma unroll
    for (int i=0;i<9;i++) R[i]=rs[i];
  }
  float jx=0.f, jy=0.f, jz=0.f;
  if (act){ jx=jlds[j*3+0]; jy=jlds[j*3+1]; jz=jlds[j*3+2]; }
  int par = act ? c_parents[j] : 0;
  if (par < 0) par = 0;
  float px = __shfl(jx, par), py = __shfl(jy, par), pz = __shfl(jz, par);
  float t0, t1, t2;
  if (j == 0){ t0=jx; t1=jy; t2=jz; }
  else       { t0=jx-px; t1=jy-py; t2=jz-pz; }

  float M[12];
  #pragma unroll
  for (int r=0;r<3;r++){
    M[r*4+0]=R[r*3+0]; M[r*4+1]=R[r*3+1]; M[r*4+2]=R[r*3+2]; M[r*4+3]= (r==0?t0:(r==1?t1:t2));
  }
  int dep = act ? c_depth[j] : 99;

  #pragma unroll
  for (int L=1; L<=10; L++){
    float pm[12];
    #pragma unroll
    for (int i=0;i<12;i++) pm[i] = __shfl(M[i], par);   // exec-uniform
    if (dep == L){
      #pragma unroll
      for (int r=0;r<3;r++){
        float p0=pm[r*4+0], p1=pm[r*4+1], p2=pm[r*4+2], p3=pm[r*4+3];
        M[r*4+0] = p0*R[0]+p1*R[3]+p2*R[6];
        M[r*4+1] = p0*R[1]+p1*R[4]+p2*R[7];
        M[r*4+2] = p0*R[2]+p1*R[5]+p2*R[8];
        M[r*4+3] = p0*t0 + p1*t1 + p2*t2 + p3;
      }
    }
  }

  float wx=wtsl[b*3+0], wy=wtsl[b*3+1], wz=wtsl[b*3+2];
  if (act){
    jout[((size_t)b*NJ+j)*3+0] = M[3]  + wx;
    jout[((size_t)b*NJ+j)*3+1] = M[7]  + wy;
    jout[((size_t)b*NJ+j)*3+2] = M[11] + wz;
  }
  float A[12];
  #pragma unroll
  for (int r=0;r<3;r++){
    A[r*4+0]=M[r*4+0]; A[r*4+1]=M[r*4+1]; A[r*4+2]=M[r*4+2];
    A[r*4+3]=M[r*4+3] - (M[r*4+0]*jx + M[r*4+1]*jy + M[r*4+2]*jz);
  }
  unsigned short* ah = arelb + (size_t)(b*2+0)*16*64;
  unsigned short* al = arelb + (size_t)(b*2+1)*16*64;
  #pragma unroll
  for (int e=0;e<16;e++){
    float v = (e < 12 && act) ? A[e] : 0.f;
    unsigned short hi = f2bf(v);
    float lo = v - bf2f(hi);
    ah[e*64 + j] = hi;                 // contiguous across lanes per e
    al[e*64 + j] = f2bf(lo);
  }
}

// -------- v_posed = [pf|bs|es] @ [posedirs; sdT; edT] + vt  (bf16 MFMA) -----
// B-path rebuilt: cooperative LDS staging. Each chunk's 32x64 pd tile is
// loaded with float4 coalesced loads (16B/lane, 256B/row), converted to bf16
// ONCE, stored to [k][PADC=70] LDS. Fragment reads are ds_read_u16 at bank
// (3k + col/2)%32 -> conflict-free (quad spreads {0,8,16,24}, m16/2 0..7).
// Double-buffered; regs prefetch chunk c+1 during chunk c; 1 barrier/chunk.
// Replaces 512 strided scalar global loads/lane (MLP-capped at ~1.3 TB/s in
// R6/R12) with 32 wide coalesced loads/lane.
__global__ __launch_bounds__(256) void k_vposed(
    const float* __restrict__ pd, const float* __restrict__ sd,
    const float* __restrict__ ed, const float* __restrict__ vt,
    const unsigned short* __restrict__ pfb, float* __restrict__ vsh) {
  __shared__ unsigned short bt[2][32*PADC];    // 2 x 4480 B
  const int tid  = threadIdx.x;
  const int w    = tid >> 6, lane = tid & 63;
  const int m16  = lane & 15, quad = lane >> 4;
  const int col0 = blockIdx.x * BN;
  const bool tail = (col0 + BN > VC);          // last block only

  const int sf4 = tid & 15;                    // float4 slot in row
  const int sr  = tid >> 4;                    // row 0..15 (and +16)
  const int scol = col0 + sf4*4;

  f32x4 acc[4][4];
  #pragma unroll
  for (int i=0;i<4;i++)
    #pragma unroll
    for (int j=0;j<4;j++) acc[i][j] = (f32x4){0.f,0.f,0.f,0.f};

  const unsigned short* pfa = pfb + (size_t)(w*64 + m16)*KP + quad*8;

  // wide load helper (tail block: scalar bounds-checked)
  auto LD = [&](int kk)->f32x4 {
    if (!tail) return *((const f32x4*)(pd + (size_t)kk*VC + scol));
    f32x4 r;
    #pragma unroll
    for (int i=0;i<4;i++){
      int cc = scol + i;
      r[i] = (cc < VC) ? pd[(size_t)kk*VC + cc] : 0.f;
    }
    return r;
  };
  auto STORE4 = [&](unsigned short* buf, int row, const f32x4& v){
    uint32_t p0 = (uint32_t)f2bf(v[0]) | ((uint32_t)f2bf(v[1]) << 16);
    uint32_t p1 = (uint32_t)f2bf(v[2]) | ((uint32_t)f2bf(v[3]) << 16);
    uint32_t* q = (uint32_t*)(buf + row*PADC + sf4*4);   // 4B-aligned always
    q[0] = p0; q[1] = p1;
  };

  f32x4 ra = LD(0*BKC + sr), rb = LD(0*BKC + sr + 16);   // prologue chunk 0

  for (int c = 0; c < NCHUNK; ++c){
    unsigned short* buf = &bt[c & 1][0];
    if (c < 15){
      STORE4(buf, sr,      ra);
      STORE4(buf, sr + 16, rb);
      if (c + 1 < 15){                      // prefetch next pure-pd chunk
        ra = LD((c+1)*BKC + sr);
        rb = LD((c+1)*BKC + sr + 16);
      }
    } else {
      // chunk 15: rows 480..485 pd, 486..505 sd/ed, 506..511 zero (scalar)
      int colL = tid & 63, rg = tid >> 6;
      int colG = col0 + colL;
      if (colG < VC){
        int n3 = colG/3, c3 = colG - n3*3;
        const float* sp = sd + (size_t)n3*30 + c3*10;
        const float* ep = ed + (size_t)n3*30 + c3*10;
        #pragma unroll
        for (int rr = 0; rr < 8; rr++){
          int r = rg*8 + rr;
          int kk = 480 + r;
          float f = 0.f;
          if (kk < PB)      f = pd[(size_t)kk*VC + colG];
          else if (kk < KS){
            int q = kk - PB;
            f = (q < 10) ? sp[q] : ep[q-10];
          }
          buf[r*PADC + colL] = f2bf(f);
        }
      } else {
        #pragma unroll
        for (int rr = 0; rr < 8; rr++) buf[(rg*8+rr)*PADC + colL] = 0;
      }
    }
    __syncthreads();                        // buf[c&1] ready; prev reads done

    const int k0 = c*BKC;
    bf16x8 a[4];
    #pragma unroll
    for (int mi=0;mi<4;mi++)
      a[mi] = *((const bf16x8*)(pfa + (size_t)mi*16*KP + k0));
    union { bf16x8 v; unsigned short s[8]; } bb[4];
    #pragma unroll
    for (int ni=0;ni<4;ni++){
      #pragma unroll
      for (int j=0;j<8;j++)
        bb[ni].s[j] = buf[(quad*8 + j)*PADC + ni*16 + m16];
    }
    #pragma unroll
    for (int mi=0;mi<4;mi++)
      #pragma unroll
      for (int ni=0;ni<4;ni++)
        acc[mi][ni] = __builtin_amdgcn_mfma_f32_16x16x32_bf16(
                          a[mi], bb[ni].v, acc[mi][ni], 0, 0, 0);
  }
  // epilogue: vsh[row][col] = acc + v_template[col]
  #pragma unroll
  for (int mi=0;mi<4;mi++){
    int rbase = w*64 + mi*16 + quad*4;
    #pragma unroll
    for (int ni=0;ni<4;ni++){
      int col = col0 + ni*16 + m16;
      if (col < VC){
        float vtc = vt[col];
        #pragma unroll
        for (int r=0;r<4;r++)
          vsh[(size_t)(rbase + r)*VC + col] = acc[mi][ni][r] + vtc;
      }
    }
  }
}

// -------- skinning: operand-swapped MFMA + per-wave LDS slot + coalesced apply
// (R10-proven form: 16 batches/block, 52.9 µs, zero conflicts)
__global__ __launch_bounds__(256) void k_verts(
    const unsigned short* __restrict__ lwb, const unsigned short* __restrict__ arelb,
    const float* __restrict__ wtsl, float* __restrict__ out) {
  __shared__ float sT[4*816];              // 4 wave slots x 12 planes x 68
  const int tid = threadIdx.x, w = tid >> 6, lane = tid & 63;
  const int m16 = lane & 15, quad = lane >> 4;   // quad = T row q
  const int n0 = blockIdx.x*64;
  const int b0 = blockIdx.y*16;
  float* myT = &sT[w*816];

  bf16x8 lwh[4][2], lwl[4][2];
  #pragma unroll
  for (int vt4=0; vt4<4; vt4++){
    int row = n0 + vt4*16 + m16;
    #pragma unroll
    for (int kc=0;kc<2;kc++){
      lwh[vt4][kc] = *((const bf16x8*)(lwb + (size_t)row*64 + kc*32 + quad*8));
      lwl[vt4][kc] = *((const bf16x8*)(lwb + (size_t)NVP*64 + (size_t)row*64 + kc*32 + quad*8));
    }
  }
  const int nA = n0 + lane;                // apply vert for this lane
  const bool okA = (nA < NV);

  for (int bi=0; bi<4; bi++){
    const int b = b0 + w*4 + bi;
    bf16x8 ah[2], al[2];
    #pragma unroll
    for (int kc=0;kc<2;kc++){
      ah[kc] = *((const bf16x8*)(arelb + ((size_t)(b*2+0)*16 + m16)*64 + kc*32 + quad*8));
      al[kc] = *((const bf16x8*)(arelb + ((size_t)(b*2+1)*16 + m16)*64 + kc*32 + quad*8));
    }
    const float* vp = out + ((size_t)b*NV + nA)*3;
    float vx = okA ? vp[0] : 0.f;
    float vy = okA ? vp[1] : 0.f;
    float vz = okA ? vp[2] : 0.f;

    f32x4 acc[4];
    #pragma unroll
    for (int vt4=0; vt4<4; vt4++) acc[vt4] = (f32x4){0.f,0.f,0.f,0.f};
    #pragma unroll
    for (int vt4=0; vt4<4; vt4++){
      #pragma unroll
      for (int kc=0;kc<2;kc++){
        acc[vt4] = __builtin_amdgcn_mfma_f32_16x16x32_bf16(ah[kc], lwh[vt4][kc], acc[vt4], 0,0,0);
        acc[vt4] = __builtin_amdgcn_mfma_f32_16x16x32_bf16(al[kc], lwh[vt4][kc], acc[vt4], 0,0,0);
        acc[vt4] = __builtin_amdgcn_mfma_f32_16x16x32_bf16(ah[kc], lwl[vt4][kc], acc[vt4], 0,0,0);
      }
    }
    #pragma unroll
    for (int vt4=0; vt4<4; vt4++){
      if (quad < 3){
        #pragma unroll
        for (int r=0;r<4;r++)
          myT[(quad*4 + r)*68 + vt4*16 + m16] = acc[vt4][r];
      }
    }
    float T[12];
    #pragma unroll
    for (int e=0;e<12;e++) T[e] = myT[e*68 + lane];
    if (okA){
      float tx=wtsl[b*3+0], ty=wtsl[b*3+1], tz=wtsl[b*3+2];
      float* op = out + ((size_t)b*NV + nA)*3;
      op[0] = T[0]*vx + T[1]*vy + T[2] *vz + T[3]  + tx;
      op[1] = T[4]*vx + T[5]*vy + T[6] *vz + T[7]  + ty;
      op[2] = T[8]*vx + T[9]*vy + T[10]*vz + T[11] + tz;
    }
  }
}

extern "C" void kernel_launch(void* const* d_in, const int* in_sizes, int n_in,
                              void* d_out, int out_size, void* d_ws, size_t ws_size,
                              hipStream_t stream) {
  const float* wrot   = (const float*)d_in[0];
  const float* wtsl   = (const float*)d_in[1];
  const float* bshape = (const float*)d_in[2];
  const float* bpose  = (const float*)d_in[3];
  const float* lhand  = (const float*)d_in[4];
  const float* rhand  = (const float*)d_in[5];
  const float* eshape = (const float*)d_in[6];
  const float* jaw    = (const float*)d_in[7];
  const float* leye   = (const float*)d_in[8];
  const float* reye   = (const float*)d_in[9];
  const float* vt     = (const float*)d_in[10];
  const float* sd     = (const float*)d_in[11];
  const float* ed     = (const float*)d_in[12];
  const float* pd     = (const float*)d_in[13];
  const float* jreg   = (const float*)d_in[14];
  const float* lw     = (const float*)d_in[15];
  float* out = (float*)d_out;

  float* vsh  = out;                               // verts region = v_posed scratch
  float* jout = out + (size_t)BATCH*NV*3;

  float* ws   = (float*)d_ws;
  float* part = ws;                                        // 55*8*63 = 27720
  unsigned short* pfb   = (unsigned short*)(part + (size_t)NJ*JCH*63); // 256*512
  unsigned short* lwb   = pfb + (size_t)BATCH*KP;                     // 2*NVP*64
  unsigned short* arelb = lwb + (size_t)2*NVP*64;                     // 256*2*16*64

  k_front <<<FRONT_BLOCKS, 256, 0, stream>>>(lw, bpose, jaw, leye, reye,
                                             lhand, rhand, bshape, eshape,
                                             jreg, sd, ed, vt, lwb, pfb, part);
  k_mid   <<<BATCH, 256, 0, stream>>>(part, bshape, eshape, wrot, bpose, jaw,
                                      leye, reye, lhand, rhand, wtsl, arelb, jout);
  k_vposed<<<(VC+BN-1)/BN, 256, 0, stream>>>(pd, sd, ed, vt, pfb, vsh);
  k_verts <<<dim3(NVP/64, BATCH/16), 256, 0, stream>>>(lwb, arelb, wtsl, out);
}